// Round 2
// baseline (498.485 us; speedup 1.0000x reference)
//
#include <hip/hip_runtime.h>
#include <hip/hip_bf16.h>

namespace {

constexpr int kB = 8;
constexpr int kT = 2048;
constexpr int kC = 1024;
constexpr int kH = 64;
constexpr float kScale = 0.03125f;   // 1024^-0.5
constexpr int kN = kB * kT * kH;     // q/k/v element count

__global__ __launch_bounds__(256) void zero_l_kernel(float* __restrict__ l) {
  const int i = blockIdx.x * 256 + threadIdx.x;
  if (i < kB * kT) l[i] = 0.f;
}

// K1: q,k,v = x @ {Wq,Wk,Wv}. 8 rows per block; thread = (h, row-pair).
__global__ __launch_bounds__(256) void qkv_kernel(
    const float* __restrict__ x, const float* __restrict__ Wk,
    const float* __restrict__ Wq, const float* __restrict__ Wv,
    float* __restrict__ q, float* __restrict__ k, float* __restrict__ v) {
  __shared__ float xs[8 * kC];  // 32 KiB, 8 rows of x
  const int tid = threadIdx.x;
  const size_t xbase = (size_t)blockIdx.x * (8 * kC);
#pragma unroll
  for (int jj = 0; jj < 8; ++jj) {
    const int p = tid + 256 * jj;  // float4 id, 2048 total
    *reinterpret_cast<float4*>(&xs[p * 4]) =
        *reinterpret_cast<const float4*>(x + xbase + (size_t)p * 4);
  }
  __syncthreads();
  const int h = tid & 63;
  const int pr = tid >> 6;  // rows pr and pr+4
  float aq0 = 0.f, ak0 = 0.f, av0 = 0.f, aq1 = 0.f, ak1 = 0.f, av1 = 0.f;
  for (int c8 = 0; c8 < kC / 8; ++c8) {
    const int c = c8 * 8;
    float x0[8], x1[8];
    *reinterpret_cast<float4*>(&x0[0]) = *reinterpret_cast<const float4*>(&xs[pr * kC + c]);
    *reinterpret_cast<float4*>(&x0[4]) = *reinterpret_cast<const float4*>(&xs[pr * kC + c + 4]);
    *reinterpret_cast<float4*>(&x1[0]) = *reinterpret_cast<const float4*>(&xs[(pr + 4) * kC + c]);
    *reinterpret_cast<float4*>(&x1[4]) = *reinterpret_cast<const float4*>(&xs[(pr + 4) * kC + c + 4]);
#pragma unroll
    for (int j = 0; j < 8; ++j) {
      const int wi = (c + j) * kH + h;
      const float wq = Wq[wi];
      const float wk = Wk[wi];
      const float wv = Wv[wi];
      aq0 = fmaf(x0[j], wq, aq0); ak0 = fmaf(x0[j], wk, ak0); av0 = fmaf(x0[j], wv, av0);
      aq1 = fmaf(x1[j], wq, aq1); ak1 = fmaf(x1[j], wk, ak1); av1 = fmaf(x1[j], wv, av1);
    }
  }
  const size_t m0 = (size_t)blockIdx.x * 8 + pr;
  const size_t m1 = m0 + 4;
  q[m0 * kH + h] = aq0; k[m0 * kH + h] = ak0; v[m0 * kH + h] = av0;
  q[m1 * kH + h] = aq1; k[m1 * kH + h] = ak1; v[m1 * kH + h] = av1;
}

// K2: l[b,s] = sum_{t>=s} exp(scale * q_t . k_s). 128t x 64s tile per block.
__global__ __launch_bounds__(256) void colsum_kernel(
    const float* __restrict__ q, const float* __restrict__ k, float* __restrict__ l) {
  const int tj = blockIdx.x;  // t-tile of 128
  const int si = blockIdx.y;  // s-tile of 64
  const int b = blockIdx.z;
  const int t0 = tj * 128, s0 = si * 64;
  if (t0 + 127 < s0) return;  // tile entirely below diagonal
  __shared__ float kt[64][68];   // stride 68 => conflict-free float4 reads
  __shared__ float qt[128][68];
  __shared__ float red[4][64];
  const int tid = threadIdx.x;
#pragma unroll
  for (int jj = 0; jj < 4; ++jj) {
    const int p = tid + 256 * jj;
    const int row = p >> 4, c4 = p & 15;
    *reinterpret_cast<float4*>(&kt[row][c4 * 4]) =
        *reinterpret_cast<const float4*>(&k[(size_t)(b * kT + s0 + row) * kH + c4 * 4]);
  }
#pragma unroll
  for (int jj = 0; jj < 8; ++jj) {
    const int p = tid + 256 * jj;
    const int row = p >> 4, c4 = p & 15;
    *reinterpret_cast<float4*>(&qt[row][c4 * 4]) =
        *reinterpret_cast<const float4*>(&q[(size_t)(b * kT + t0 + row) * kH + c4 * 4]);
  }
  __syncthreads();
  const int s = tid & 63, tg = tid >> 6;
  float kreg[64];
#pragma unroll
  for (int c4 = 0; c4 < 16; ++c4)
    *reinterpret_cast<float4*>(&kreg[c4 * 4]) = *reinterpret_cast<const float4*>(&kt[s][c4 * 4]);
  const int gs = s0 + s;
  float lsum = 0.f;
  for (int it = 0; it < 32; ++it) {
    const int tl = tg * 32 + it;
    float d = 0.f;
#pragma unroll
    for (int c4 = 0; c4 < 16; ++c4) {
      const float4 qv = *reinterpret_cast<const float4*>(&qt[tl][c4 * 4]);
      d = fmaf(qv.x, kreg[c4 * 4 + 0], d);
      d = fmaf(qv.y, kreg[c4 * 4 + 1], d);
      d = fmaf(qv.z, kreg[c4 * 4 + 2], d);
      d = fmaf(qv.w, kreg[c4 * 4 + 3], d);
    }
    if (t0 + tl >= gs) lsum += __expf(d * kScale);
  }
  red[tg][s] = lsum;
  __syncthreads();
  if (tg == 0) {
    atomicAdd(&l[(size_t)b * kT + gs], red[0][s] + red[1][s] + red[2][s] + red[3][s]);
  }
}

// K3: out[t,h] = sum_{s<=t} exp(scale * q_t . k_s) * v[s,h] / l[s].
// 16-row t-tiles; block handles tiles (x, 127-x) for load balance.
__global__ __launch_bounds__(256) void out_kernel(
    const float* __restrict__ q, const float* __restrict__ k, const float* __restrict__ v,
    const float* __restrict__ l, float* __restrict__ out) {
  const int xpair = blockIdx.x;  // 0..63
  const int b = blockIdx.y;
  __shared__ float kt[64][68];
  __shared__ float vt[64][68];
  __shared__ float qt[16][68];
  __shared__ float P[16][68];
  const int tid = threadIdx.x;
  const int h = tid & 63, tg = tid >> 6;
#pragma unroll
  for (int tp = 0; tp < 2; ++tp) {
    const int ttile = (tp == 0) ? xpair : (127 - xpair);
    const int t0 = ttile * 16;
    __syncthreads();  // previous pass done with qt
    {
      const int row = tid >> 4, c4 = tid & 15;  // 256 threads = 16 rows x 16 c4
      *reinterpret_cast<float4*>(&qt[row][c4 * 4]) =
          *reinterpret_cast<const float4*>(&q[(size_t)(b * kT + t0 + row) * kH + c4 * 4]);
    }
    float acc[4] = {0.f, 0.f, 0.f, 0.f};
    const int njs = (t0 + 15) / 64 + 1;  // s-tiles touching t<=t0+15
    for (int sj = 0; sj < njs; ++sj) {
      const int s0 = sj * 64;
      __syncthreads();  // previous phase2 done with kt/vt/P
#pragma unroll
      for (int jj = 0; jj < 4; ++jj) {
        const int p = tid + 256 * jj;
        const int row = p >> 4, c4 = p & 15;
        const size_t gr = (size_t)(b * kT + s0 + row) * kH + c4 * 4;
        *reinterpret_cast<float4*>(&kt[row][c4 * 4]) = *reinterpret_cast<const float4*>(&k[gr]);
        const float rl = 1.0f / l[(size_t)b * kT + s0 + row];
        float4 vv = *reinterpret_cast<const float4*>(&v[gr]);
        vv.x *= rl; vv.y *= rl; vv.z *= rl; vv.w *= rl;
        *reinterpret_cast<float4*>(&vt[row][c4 * 4]) = vv;
      }
      __syncthreads();
      // phase1: scores for column s=h, rows tg*4+it
      float kreg[64];
#pragma unroll
      for (int c4 = 0; c4 < 16; ++c4)
        *reinterpret_cast<float4*>(&kreg[c4 * 4]) = *reinterpret_cast<const float4*>(&kt[h][c4 * 4]);
      const int gscol = s0 + h;
#pragma unroll
      for (int it = 0; it < 4; ++it) {
        const int tl = tg * 4 + it;
        float d = 0.f;
#pragma unroll
        for (int c4 = 0; c4 < 16; ++c4) {
          const float4 qv = *reinterpret_cast<const float4*>(&qt[tl][c4 * 4]);
          d = fmaf(qv.x, kreg[c4 * 4 + 0], d);
          d = fmaf(qv.y, kreg[c4 * 4 + 1], d);
          d = fmaf(qv.z, kreg[c4 * 4 + 2], d);
          d = fmaf(qv.w, kreg[c4 * 4 + 3], d);
        }
        P[tl][h] = (t0 + tl >= gscol) ? __expf(d * kScale) : 0.f;
      }
      __syncthreads();
      // phase2: acc[rr] += P[row][s] * vhat[s][h]
#pragma unroll
      for (int s4 = 0; s4 < 16; ++s4) {
        const float vv0 = vt[s4 * 4 + 0][h];
        const float vv1 = vt[s4 * 4 + 1][h];
        const float vv2 = vt[s4 * 4 + 2][h];
        const float vv3 = vt[s4 * 4 + 3][h];
#pragma unroll
        for (int rr = 0; rr < 4; ++rr) {
          const float4 p4 = *reinterpret_cast<const float4*>(&P[tg * 4 + rr][s4 * 4]);
          acc[rr] = fmaf(p4.x, vv0, acc[rr]);
          acc[rr] = fmaf(p4.y, vv1, acc[rr]);
          acc[rr] = fmaf(p4.z, vv2, acc[rr]);
          acc[rr] = fmaf(p4.w, vv3, acc[rr]);
        }
      }
    }
#pragma unroll
    for (int rr = 0; rr < 4; ++rr) {
      const int gt = t0 + tg * 4 + rr;
      out[(size_t)(b * kT + gt) * kH + h] = acc[rr];
    }
  }
}

}  // namespace

extern "C" void kernel_launch(void* const* d_in, const int* in_sizes, int n_in,
                              void* d_out, int out_size, void* d_ws, size_t ws_size,
                              hipStream_t stream) {
  const float* x = (const float*)d_in[0];
  const float* Wk = (const float*)d_in[1];
  const float* Wq = (const float*)d_in[2];
  const float* Wv = (const float*)d_in[3];
  float* q = (float*)d_ws;
  float* k = q + kN;
  float* v = k + kN;
  float* l = v + kN;
  float* out = (float*)d_out;

  zero_l_kernel<<<dim3(64), dim3(256), 0, stream>>>(l);
  qkv_kernel<<<dim3(kB * kT / 8), dim3(256), 0, stream>>>(x, Wk, Wq, Wv, q, k, v);
  colsum_kernel<<<dim3(16, 32, kB), dim3(256), 0, stream>>>(q, k, l);
  out_kernel<<<dim3(64, kB), dim3(256), 0, stream>>>(q, k, v, l, out);
}

// Round 3
// 158.857 us; speedup vs baseline: 3.1379x; 3.1379x over previous
//
#include <hip/hip_runtime.h>
#include <hip/hip_bf16.h>

namespace {

typedef unsigned short u16;
typedef __attribute__((ext_vector_type(8))) short bf16x8;
typedef __attribute__((ext_vector_type(4))) float f32x4;

constexpr int kB = 8, kT = 2048, kC = 1024, kH = 64;
constexpr float kScale = 0.03125f;  // 1024^-0.5

// workspace layout in u16 elements
constexpr size_t kWtOff = 0;                        // 3*64*1024
constexpr size_t kQbOff = kWtOff + 3 * 64 * 1024;   // 16384*64
constexpr size_t kKbOff = kQbOff + 16384 * 64;
constexpr size_t kVtOff = kKbOff + 16384 * 64;      // v transposed [b*64+h][t]
constexpr size_t kLOff  = kVtOff + 16384 * 64;      // float l[16384] starts here

__device__ __forceinline__ u16 f2bu(float f) {
  __hip_bfloat16 h = __float2bfloat16(f);
  return *reinterpret_cast<u16*>(&h);
}

__device__ __forceinline__ f32x4 mfma16(bf16x8 a, bf16x8 b, f32x4 c) {
  return __builtin_amdgcn_mfma_f32_16x16x32_bf16(a, b, c, 0, 0, 0);
}

// K0: Wt[mat][h][c] = bf16(W[c][h])
__global__ __launch_bounds__(256) void wt_kernel(
    const float* __restrict__ Wk, const float* __restrict__ Wq,
    const float* __restrict__ Wv, u16* __restrict__ Wt) {
  __shared__ float wsm[64 * 65];
  const int c0 = blockIdx.x * 64;
  const int mat = blockIdx.y;
  const float* W = (mat == 0) ? Wk : (mat == 1) ? Wq : Wv;
  const int tid = threadIdx.x;
#pragma unroll
  for (int ii = 0; ii < 4; ++ii) {
    const int p = tid + 256 * ii;          // float4 chunk: 1024 total
    const int row = p >> 4, col4 = p & 15;
    const float4 wv = *reinterpret_cast<const float4*>(&W[(size_t)(c0 + row) * 64 + col4 * 4]);
    wsm[row * 65 + col4 * 4 + 0] = wv.x;
    wsm[row * 65 + col4 * 4 + 1] = wv.y;
    wsm[row * 65 + col4 * 4 + 2] = wv.z;
    wsm[row * 65 + col4 * 4 + 3] = wv.w;
  }
  __syncthreads();
  const int h = tid & 63, seg = tid >> 6;
#pragma unroll
  for (int i = 0; i < 16; ++i) {
    const int c = seg * 16 + i;
    Wt[((size_t)mat * 64 + h) * 1024 + c0 + c] = f2bu(wsm[c * 65 + h]);
  }
}

// K1: fused q,k,v GEMM.  M-tile 64, N = 192 (k|q|v).  x staged f32->bf16 in
// swizzled LDS; Wt fragments direct from global (L2).
__global__ __launch_bounds__(256) void qkv_kernel(
    const float* __restrict__ x, const u16* __restrict__ Wt,
    u16* __restrict__ qb, u16* __restrict__ kb, u16* __restrict__ vt) {
  __shared__ u16 xs[64 * 64];  // 8 KiB, XOR-swizzled on u16-index bits 3..5
  const int tid = threadIdx.x;
  const int lane = tid & 63, w = tid >> 6;
  const int l15 = lane & 15, l4 = lane >> 4;
  const int m0 = blockIdx.x * 64;

  f32x4 acc[12];
#pragma unroll
  for (int nf = 0; nf < 12; ++nf) acc[nf] = f32x4{0.f, 0.f, 0.f, 0.f};

  for (int k0 = 0; k0 < kC; k0 += 64) {
    __syncthreads();
    // stage 64 rows x 64 k of x as bf16 (coalesced float4 loads)
#pragma unroll
    for (int ii = 0; ii < 4; ++ii) {
      const int c = tid + 256 * ii;         // 1024 float4 chunks
      const int row = c >> 4, cseg = c & 15;
      const float4 xv = *reinterpret_cast<const float4*>(
          &x[(size_t)(m0 + row) * kC + k0 + cseg * 4]);
      uint2 pk;
      pk.x = (unsigned)f2bu(xv.x) | ((unsigned)f2bu(xv.y) << 16);
      pk.y = (unsigned)f2bu(xv.z) | ((unsigned)f2bu(xv.w) << 16);
      const int idx = (row * 64 + cseg * 4) ^ ((row & 7) << 3);
      *reinterpret_cast<uint2*>(&xs[idx]) = pk;
    }
    __syncthreads();
    const int arow = 16 * w + l15;
    const bf16x8 a0 = *reinterpret_cast<const bf16x8*>(
        &xs[(arow * 64 + (0 + l4) * 8) ^ ((arow & 7) << 3)]);
    const bf16x8 a1 = *reinterpret_cast<const bf16x8*>(
        &xs[(arow * 64 + (4 + l4) * 8) ^ ((arow & 7) << 3)]);
#pragma unroll
    for (int nf = 0; nf < 12; ++nf) {
      const u16* wp = Wt + ((size_t)((nf >> 2) * 64 + (nf & 3) * 16 + l15)) * 1024 + k0 + 8 * l4;
      const bf16x8 b0 = *reinterpret_cast<const bf16x8*>(wp);
      const bf16x8 b1 = *reinterpret_cast<const bf16x8*>(wp + 32);
      acc[nf] = mfma16(a0, b0, acc[nf]);
      acc[nf] = mfma16(a1, b1, acc[nf]);
    }
  }
  // store: D row = 4*l4+r (local), col = 16*(nf&3)+l15
#pragma unroll
  for (int nf = 0; nf < 12; ++nf) {
    const int mat = nf >> 2;
    const int hcol = (nf & 3) * 16 + l15;
#pragma unroll
    for (int r = 0; r < 4; ++r) {
      const int m = m0 + 16 * w + 4 * l4 + r;
      const u16 val = f2bu(acc[nf][r]);
      if (mat == 0) kb[(size_t)m * 64 + hcol] = val;
      else if (mat == 1) qb[(size_t)m * 64 + hcol] = val;
      else {
        const int bb = m >> 11, t = m & 2047;
        vt[((size_t)(bb * 64 + hcol)) * 2048 + t] = val;
      }
    }
  }
}

// K2: l[b,s] = sum_{t>=s} exp(scale * q_t.k_s).  mfma(A=K, B=Q) -> D[s][t].
// s-tile 64 per block; wave w covers t in [tc+128w, tc+128w+127].  No LDS.
__global__ __launch_bounds__(256) void colsum_kernel(
    const u16* __restrict__ qb, const u16* __restrict__ kb, float* __restrict__ lG) {
  const int s0 = blockIdx.x * 64;
  const int tc = blockIdx.y * 512;
  const int b = blockIdx.z;
  if (tc + 511 < s0) return;
  const int tid = threadIdx.x;
  const int lane = tid & 63, w = tid >> 6;
  const int l15 = lane & 15, l4 = lane >> 4;

  bf16x8 ka[4][2];
#pragma unroll
  for (int i = 0; i < 4; ++i) {
    const u16* kp = kb + (size_t)(b * kT + s0 + 16 * i + l15) * 64 + 8 * l4;
    ka[i][0] = *reinterpret_cast<const bf16x8*>(kp);
    ka[i][1] = *reinterpret_cast<const bf16x8*>(kp + 32);
  }
  f32x4 cs[4];
#pragma unroll
  for (int i = 0; i < 4; ++i) cs[i] = f32x4{0.f, 0.f, 0.f, 0.f};

  for (int j = 0; j < 8; ++j) {
    const int tj = tc + 128 * w + 16 * j;
    if (tj + 15 < s0) continue;  // frag entirely below diagonal
    const u16* qp = qb + (size_t)(b * kT + tj + l15) * 64 + 8 * l4;
    const bf16x8 qf0 = *reinterpret_cast<const bf16x8*>(qp);
    const bf16x8 qf1 = *reinterpret_cast<const bf16x8*>(qp + 32);
    const int t = tj + l15;
#pragma unroll
    for (int i = 0; i < 4; ++i) {
      f32x4 d = f32x4{0.f, 0.f, 0.f, 0.f};
      d = mfma16(ka[i][0], qf0, d);
      d = mfma16(ka[i][1], qf1, d);
#pragma unroll
      for (int r = 0; r < 4; ++r) {
        const int s = s0 + 16 * i + 4 * l4 + r;
        if (t >= s) cs[i][r] += __expf(d[r] * kScale);
      }
    }
  }
  // reduce over 16 t-cols (lanes within 16-group), then atomicAdd per s
#pragma unroll
  for (int i = 0; i < 4; ++i) {
#pragma unroll
    for (int r = 0; r < 4; ++r) {
      float v = cs[i][r];
      v += __shfl_xor(v, 1, 64);
      v += __shfl_xor(v, 2, 64);
      v += __shfl_xor(v, 4, 64);
      v += __shfl_xor(v, 8, 64);
      if (l15 == 0) atomicAdd(&lG[b * kT + s0 + 16 * i + 4 * l4 + r], v);
    }
  }
}

// K3: out[t,h] += sum_{s<=t} exp(scale*q.k)/l[s] * v[s,h].
// t-tile 64 (wave w owns rows t0+16w..+15, wave-private LDS P).  s-parity split
// across 2 blocks; f32 atomicAdd into zeroed out (2 contributors => exact).
__global__ __launch_bounds__(256) void out_kernel(
    const u16* __restrict__ qb, const u16* __restrict__ kb, const u16* __restrict__ vt,
    const float* __restrict__ lG, float* __restrict__ out) {
  __shared__ u16 pl[4096];  // 4 waves x [16][64] bf16, XOR-swizzled
  const int tt = blockIdx.x >> 1, par = blockIdx.x & 1;
  const int b = blockIdx.y;
  const int t0 = tt * 64;
  const int tid = threadIdx.x;
  const int lane = tid & 63, w = tid >> 6;
  const int l15 = lane & 15, l4 = lane >> 4;
  const int wbu = w * 1024;

  const u16* qp = qb + (size_t)(b * kT + t0 + 16 * w + l15) * 64 + 8 * l4;
  const bf16x8 qf0 = *reinterpret_cast<const bf16x8*>(qp);
  const bf16x8 qf1 = *reinterpret_cast<const bf16x8*>(qp + 32);

  f32x4 acc[4];
#pragma unroll
  for (int nf = 0; nf < 4; ++nf) acc[nf] = f32x4{0.f, 0.f, 0.f, 0.f};

  for (int js = par; js <= tt; js += 2) {
    const int s0 = js * 64;
    // QK^T + P -> LDS
#pragma unroll
    for (int jf = 0; jf < 4; ++jf) {
      const u16* kp = kb + (size_t)(b * kT + s0 + 16 * jf + l15) * 64 + 8 * l4;
      const bf16x8 kf0 = *reinterpret_cast<const bf16x8*>(kp);
      const bf16x8 kf1 = *reinterpret_cast<const bf16x8*>(kp + 32);
      f32x4 d = f32x4{0.f, 0.f, 0.f, 0.f};
      d = mfma16(qf0, kf0, d);
      d = mfma16(qf1, kf1, d);
      const int s = s0 + 16 * jf + l15;
      const float rl = 1.0f / lG[b * kT + s];
#pragma unroll
      for (int r = 0; r < 4; ++r) {
        const int rr = 4 * l4 + r;
        const int t = t0 + 16 * w + rr;
        const float p = (t >= s) ? __expf(d[r] * kScale) * rl : 0.f;
        pl[(wbu + rr * 64 + 16 * jf + l15) ^ ((rr & 7) << 3)] = f2bu(p);
      }
    }
    // PV: A = P from LDS (16B swizzled reads), B = V^T frags from global
    const bf16x8 pa0 = *reinterpret_cast<const bf16x8*>(
        &pl[(wbu + l15 * 64 + (0 + l4) * 8) ^ ((l15 & 7) << 3)]);
    const bf16x8 pa1 = *reinterpret_cast<const bf16x8*>(
        &pl[(wbu + l15 * 64 + (4 + l4) * 8) ^ ((l15 & 7) << 3)]);
#pragma unroll
    for (int nf = 0; nf < 4; ++nf) {
      const u16* vp = vt + (size_t)(b * 64 + 16 * nf + l15) * kT + s0 + 8 * l4;
      const bf16x8 vf0 = *reinterpret_cast<const bf16x8*>(vp);
      const bf16x8 vf1 = *reinterpret_cast<const bf16x8*>(vp + 32);
      acc[nf] = mfma16(pa0, vf0, acc[nf]);
      acc[nf] = mfma16(pa1, vf1, acc[nf]);
    }
  }
#pragma unroll
  for (int nf = 0; nf < 4; ++nf) {
#pragma unroll
    for (int r = 0; r < 4; ++r) {
      const size_t oi = (size_t)(b * kT + t0 + 16 * w + 4 * l4 + r) * 64 + 16 * nf + l15;
      atomicAdd(&out[oi], acc[nf][r]);
    }
  }
}

}  // namespace

extern "C" void kernel_launch(void* const* d_in, const int* in_sizes, int n_in,
                              void* d_out, int out_size, void* d_ws, size_t ws_size,
                              hipStream_t stream) {
  const float* x = (const float*)d_in[0];
  const float* Wk = (const float*)d_in[1];
  const float* Wq = (const float*)d_in[2];
  const float* Wv = (const float*)d_in[3];
  u16* wsu = (u16*)d_ws;
  u16* Wt = wsu + kWtOff;
  u16* qb = wsu + kQbOff;
  u16* kb = wsu + kKbOff;
  u16* vt = wsu + kVtOff;
  float* lG = (float*)(wsu + kLOff);
  float* out = (float*)d_out;

  hipMemsetAsync(lG, 0, kB * kT * sizeof(float), stream);
  hipMemsetAsync(out, 0, (size_t)kB * kT * kH * sizeof(float), stream);
  wt_kernel<<<dim3(16, 3), dim3(256), 0, stream>>>(Wk, Wq, Wv, Wt);
  qkv_kernel<<<dim3(kB * kT / 64), dim3(256), 0, stream>>>(x, Wt, qb, kb, vt);
  colsum_kernel<<<dim3(kT / 64, 4, kB), dim3(256), 0, stream>>>(qb, kb, lG);
  out_kernel<<<dim3(2 * kT / 64, kB), dim3(256), 0, stream>>>(qb, kb, vt, lG, out);
}

// Round 4
// 155.130 us; speedup vs baseline: 3.2133x; 1.0240x over previous
//
#include <hip/hip_runtime.h>
#include <hip/hip_bf16.h>

namespace {

typedef unsigned short u16;
typedef __attribute__((ext_vector_type(8))) short bf16x8;
typedef __attribute__((ext_vector_type(4))) float f32x4;

constexpr int kB = 8, kT = 2048, kC = 1024, kH = 64;
constexpr float kScale = 0.03125f;  // 1024^-0.5

// workspace layout in u16 elements
constexpr size_t kWtOff = 0;                                 // 3*64*1024
constexpr size_t kQbOff = kWtOff + 3 * 64 * 1024;            // 16384*64
constexpr size_t kKbOff = kQbOff + (size_t)16384 * 64;
constexpr size_t kVtOff = kKbOff + (size_t)16384 * 64;       // v^T [b*64+h][t]
constexpr size_t kLOff  = kVtOff + (size_t)16384 * 64;       // float l[16384]

__device__ __forceinline__ u16 f2bu(float f) {
  __hip_bfloat16 h = __float2bfloat16(f);
  return *reinterpret_cast<u16*>(&h);
}
__device__ __forceinline__ short f2bs(float f) {
  __hip_bfloat16 h = __float2bfloat16(f);
  return *reinterpret_cast<short*>(&h);
}
__device__ __forceinline__ f32x4 mfma16(bf16x8 a, bf16x8 b, f32x4 c) {
  return __builtin_amdgcn_mfma_f32_16x16x32_bf16(a, b, c, 0, 0, 0);
}

// K0: Wt[mat][h][c] = bf16(W[c][h])
__global__ __launch_bounds__(256) void wt_kernel(
    const float* __restrict__ Wk, const float* __restrict__ Wq,
    const float* __restrict__ Wv, u16* __restrict__ Wt) {
  __shared__ float wsm[64 * 65];
  const int c0 = blockIdx.x * 64;
  const int mat = blockIdx.y;
  const float* W = (mat == 0) ? Wk : (mat == 1) ? Wq : Wv;
  const int tid = threadIdx.x;
#pragma unroll
  for (int ii = 0; ii < 4; ++ii) {
    const int p = tid + 256 * ii;
    const int row = p >> 4, col4 = p & 15;
    const float4 wv = *reinterpret_cast<const float4*>(&W[(size_t)(c0 + row) * 64 + col4 * 4]);
    wsm[row * 65 + col4 * 4 + 0] = wv.x;
    wsm[row * 65 + col4 * 4 + 1] = wv.y;
    wsm[row * 65 + col4 * 4 + 2] = wv.z;
    wsm[row * 65 + col4 * 4 + 3] = wv.w;
  }
  __syncthreads();
  const int h = tid & 63, seg = tid >> 6;
#pragma unroll
  for (int i = 0; i < 16; ++i) {
    const int c = seg * 16 + i;
    Wt[((size_t)mat * 64 + h) * 1024 + c0 + c] = f2bu(wsm[c * 65 + h]);
  }
}

// K1: fused q,k,v GEMM. 1 wave per block, M-tile 16, zero barriers.
// A-frags converted f32->bf16 straight from global x; B-frags from Wt (L2).
__global__ __launch_bounds__(64) void qkv_kernel(
    const float* __restrict__ x, const u16* __restrict__ Wt,
    u16* __restrict__ qb, u16* __restrict__ kb, u16* __restrict__ vt) {
  const int lane = threadIdx.x;
  const int l15 = lane & 15, l4 = lane >> 4;
  const int m0 = blockIdx.x * 16;

  f32x4 acc[12];
#pragma unroll
  for (int nf = 0; nf < 12; ++nf) acc[nf] = f32x4{0.f, 0.f, 0.f, 0.f};

  const float* xp = x + (size_t)(m0 + l15) * kC + 8 * l4;
  const u16* wb = Wt + (size_t)l15 * 1024 + 8 * l4;

#pragma unroll 2
  for (int k0 = 0; k0 < kC; k0 += 32) {
    const float4 xa = *reinterpret_cast<const float4*>(xp + k0);
    const float4 xb = *reinterpret_cast<const float4*>(xp + k0 + 4);
    bf16x8 a;
    a[0] = f2bs(xa.x); a[1] = f2bs(xa.y); a[2] = f2bs(xa.z); a[3] = f2bs(xa.w);
    a[4] = f2bs(xb.x); a[5] = f2bs(xb.y); a[6] = f2bs(xb.z); a[7] = f2bs(xb.w);
#pragma unroll
    for (int nf = 0; nf < 12; ++nf) {
      const bf16x8 bfrag = *reinterpret_cast<const bf16x8*>(
          wb + ((size_t)((nf >> 2) * 64 + (nf & 3) * 16)) * 1024 + k0);
      acc[nf] = mfma16(a, bfrag, acc[nf]);
    }
  }
  // D: row = 4*l4 + r, col = 16*(nf&3) + l15
#pragma unroll
  for (int nf = 0; nf < 12; ++nf) {
    const int mat = nf >> 2;
    const int hcol = (nf & 3) * 16 + l15;
#pragma unroll
    for (int r = 0; r < 4; ++r) {
      const int m = m0 + 4 * l4 + r;
      const u16 val = f2bu(acc[nf][r]);
      if (mat == 0) kb[(size_t)m * 64 + hcol] = val;
      else if (mat == 1) qb[(size_t)m * 64 + hcol] = val;
      else vt[((size_t)((m >> 11) * 64 + hcol)) * 2048 + (m & 2047)] = val;
    }
  }
}

// K2: l[b,s] = sum_{t>=s} exp(scale * q_t.k_s).  mfma(A=K, B=Q) -> D[s][t].
__global__ __launch_bounds__(256) void colsum_kernel(
    const u16* __restrict__ qb, const u16* __restrict__ kb, float* __restrict__ lG) {
  const int s0 = blockIdx.x * 64;
  const int tc = blockIdx.y * 512;
  const int b = blockIdx.z;
  if (tc + 511 < s0) return;
  const int tid = threadIdx.x;
  const int lane = tid & 63, w = tid >> 6;
  const int l15 = lane & 15, l4 = lane >> 4;

  bf16x8 ka[4][2];
#pragma unroll
  for (int i = 0; i < 4; ++i) {
    const u16* kp = kb + (size_t)(b * kT + s0 + 16 * i + l15) * 64 + 8 * l4;
    ka[i][0] = *reinterpret_cast<const bf16x8*>(kp);
    ka[i][1] = *reinterpret_cast<const bf16x8*>(kp + 32);
  }
  f32x4 cs[4];
#pragma unroll
  for (int i = 0; i < 4; ++i) cs[i] = f32x4{0.f, 0.f, 0.f, 0.f};

  for (int j = 0; j < 8; ++j) {
    const int tj = tc + 128 * w + 16 * j;
    if (tj + 15 < s0) continue;
    const u16* qp = qb + (size_t)(b * kT + tj + l15) * 64 + 8 * l4;
    const bf16x8 qf0 = *reinterpret_cast<const bf16x8*>(qp);
    const bf16x8 qf1 = *reinterpret_cast<const bf16x8*>(qp + 32);
    const int t = tj + l15;
#pragma unroll
    for (int i = 0; i < 4; ++i) {
      f32x4 d = f32x4{0.f, 0.f, 0.f, 0.f};
      d = mfma16(ka[i][0], qf0, d);
      d = mfma16(ka[i][1], qf1, d);
#pragma unroll
      for (int r = 0; r < 4; ++r) {
        const int s = s0 + 16 * i + 4 * l4 + r;
        if (t >= s) cs[i][r] += __expf(d[r] * kScale);
      }
    }
  }
#pragma unroll
  for (int i = 0; i < 4; ++i) {
#pragma unroll
    for (int r = 0; r < 4; ++r) {
      float v = cs[i][r];
      v += __shfl_xor(v, 1, 64);
      v += __shfl_xor(v, 2, 64);
      v += __shfl_xor(v, 4, 64);
      v += __shfl_xor(v, 8, 64);
      if (l15 == 0) atomicAdd(&lG[b * kT + s0 + 16 * i + 4 * l4 + r], v);
    }
  }
}

// K3: out[t,h] += sum_{s<=t} exp(scale*q.k)/l[s] * v[s,h].
// 1 wave per block, t-tile 16, s-parity split (2 atomic contributors -> exact).
__global__ __launch_bounds__(64) void out_kernel(
    const u16* __restrict__ qb, const u16* __restrict__ kb, const u16* __restrict__ vt,
    const float* __restrict__ lG, float* __restrict__ out) {
  __shared__ u16 pl[1024];  // [16][64] bf16, XOR-swizzled, wave-private
  const int tt = blockIdx.x >> 1, par = blockIdx.x & 1;
  const int b = blockIdx.y;
  const int t0 = tt * 16;
  const int lane = threadIdx.x;
  const int l15 = lane & 15, l4 = lane >> 4;

  const u16* qp = qb + (size_t)(b * kT + t0 + l15) * 64 + 8 * l4;
  const bf16x8 qf0 = *reinterpret_cast<const bf16x8*>(qp);
  const bf16x8 qf1 = *reinterpret_cast<const bf16x8*>(qp + 32);

  f32x4 acc[4];
#pragma unroll
  for (int nf = 0; nf < 4; ++nf) acc[nf] = f32x4{0.f, 0.f, 0.f, 0.f};

  const int njs = (t0 + 15) / 64 + 1;
  for (int js = par; js < njs; js += 2) {
    const int s0 = js * 64;
    // QK^T -> P -> wave-private LDS
#pragma unroll
    for (int jf = 0; jf < 4; ++jf) {
      const u16* kp = kb + (size_t)(b * kT + s0 + 16 * jf + l15) * 64 + 8 * l4;
      const bf16x8 kf0 = *reinterpret_cast<const bf16x8*>(kp);
      const bf16x8 kf1 = *reinterpret_cast<const bf16x8*>(kp + 32);
      f32x4 d = f32x4{0.f, 0.f, 0.f, 0.f};
      d = mfma16(qf0, kf0, d);
      d = mfma16(qf1, kf1, d);
      const int s = s0 + 16 * jf + l15;
      const float rl = 1.0f / lG[b * kT + s];
#pragma unroll
      for (int r = 0; r < 4; ++r) {
        const int rr = 4 * l4 + r;
        const float p = (t0 + rr >= s) ? __expf(d[r] * kScale) * rl : 0.f;
        pl[(rr * 64 + 16 * jf + l15) ^ ((rr & 7) << 3)] = f2bu(p);
      }
    }
    // PV: A = P (swizzled 16B reads), B = V^T frags from global
    const bf16x8 pa0 = *reinterpret_cast<const bf16x8*>(
        &pl[(l15 * 64 + 8 * l4) ^ ((l15 & 7) << 3)]);
    const bf16x8 pa1 = *reinterpret_cast<const bf16x8*>(
        &pl[(l15 * 64 + 32 + 8 * l4) ^ ((l15 & 7) << 3)]);
#pragma unroll
    for (int nf = 0; nf < 4; ++nf) {
      const u16* vp = vt + (size_t)(b * 64 + 16 * nf + l15) * kT + s0 + 8 * l4;
      const bf16x8 vf0 = *reinterpret_cast<const bf16x8*>(vp);
      const bf16x8 vf1 = *reinterpret_cast<const bf16x8*>(vp + 32);
      acc[nf] = mfma16(pa0, vf0, acc[nf]);
      acc[nf] = mfma16(pa1, vf1, acc[nf]);
    }
  }
#pragma unroll
  for (int nf = 0; nf < 4; ++nf) {
#pragma unroll
    for (int r = 0; r < 4; ++r) {
      const size_t oi = (size_t)(b * kT + t0 + 4 * l4 + r) * 64 + 16 * nf + l15;
      atomicAdd(&out[oi], acc[nf][r]);
    }
  }
}

}  // namespace

extern "C" void kernel_launch(void* const* d_in, const int* in_sizes, int n_in,
                              void* d_out, int out_size, void* d_ws, size_t ws_size,
                              hipStream_t stream) {
  const float* x = (const float*)d_in[0];
  const float* Wk = (const float*)d_in[1];
  const float* Wq = (const float*)d_in[2];
  const float* Wv = (const float*)d_in[3];
  u16* wsu = (u16*)d_ws;
  u16* Wt = wsu + kWtOff;
  u16* qb = wsu + kQbOff;
  u16* kb = wsu + kKbOff;
  u16* vt = wsu + kVtOff;
  float* lG = (float*)(wsu + kLOff);
  float* out = (float*)d_out;

  hipMemsetAsync(lG, 0, kB * kT * sizeof(float), stream);
  hipMemsetAsync(out, 0, (size_t)kB * kT * kH * sizeof(float), stream);
  wt_kernel<<<dim3(16, 3), dim3(256), 0, stream>>>(Wk, Wq, Wv, Wt);
  qkv_kernel<<<dim3(kB * kT / 16), dim3(64), 0, stream>>>(x, Wt, qb, kb, vt);
  colsum_kernel<<<dim3(kT / 64, 4, kB), dim3(256), 0, stream>>>(qb, kb, lG);
  out_kernel<<<dim3(2 * kT / 16, kB), dim3(64), 0, stream>>>(qb, kb, vt, lG, out);
}

// Round 5
// 139.222 us; speedup vs baseline: 3.5805x; 1.1143x over previous
//
#include <hip/hip_runtime.h>
#include <hip/hip_bf16.h>

namespace {

typedef unsigned short u16;
typedef __attribute__((ext_vector_type(8))) short bf16x8;
typedef __attribute__((ext_vector_type(4))) float f32x4;

constexpr int kB = 8, kT = 2048, kC = 1024, kH = 64;
constexpr float kScale = 0.03125f;  // 1024^-0.5

// workspace layout in u16 elements
constexpr size_t kWtOff = 0;                                 // 3*64*1024
constexpr size_t kQbOff = kWtOff + 3 * 64 * 1024;            // 16384*64
constexpr size_t kKbOff = kQbOff + (size_t)16384 * 64;
constexpr size_t kVtOff = kKbOff + (size_t)16384 * 64;       // v^T [b*64+h][t]
constexpr size_t kLOff  = kVtOff + (size_t)16384 * 64;       // float l[16384]

__device__ __forceinline__ u16 f2bu(float f) {
  __hip_bfloat16 h = __float2bfloat16(f);
  return *reinterpret_cast<u16*>(&h);
}
__device__ __forceinline__ f32x4 mfma16(bf16x8 a, bf16x8 b, f32x4 c) {
  return __builtin_amdgcn_mfma_f32_16x16x32_bf16(a, b, c, 0, 0, 0);
}

// K0: Wt[mat][h][c] = bf16(W[c][h])
__global__ __launch_bounds__(256) void wt_kernel(
    const float* __restrict__ Wk, const float* __restrict__ Wq,
    const float* __restrict__ Wv, u16* __restrict__ Wt) {
  __shared__ float wsm[64 * 65];
  const int c0 = blockIdx.x * 64;
  const int mat = blockIdx.y;
  const float* W = (mat == 0) ? Wk : (mat == 1) ? Wq : Wv;
  const int tid = threadIdx.x;
#pragma unroll
  for (int ii = 0; ii < 4; ++ii) {
    const int p = tid + 256 * ii;
    const int row = p >> 4, col4 = p & 15;
    const float4 wv = *reinterpret_cast<const float4*>(&W[(size_t)(c0 + row) * 64 + col4 * 4]);
    wsm[row * 65 + col4 * 4 + 0] = wv.x;
    wsm[row * 65 + col4 * 4 + 1] = wv.y;
    wsm[row * 65 + col4 * 4 + 2] = wv.z;
    wsm[row * 65 + col4 * 4 + 3] = wv.w;
  }
  __syncthreads();
  const int h = tid & 63, seg = tid >> 6;
#pragma unroll
  for (int i = 0; i < 16; ++i) {
    const int c = seg * 16 + i;
    Wt[((size_t)mat * 64 + h) * 1024 + c0 + c] = f2bu(wsm[c * 65 + h]);
  }
}

// K1: fused q,k,v GEMM. 4-wave blocks, M-tile 16 shared, N-split by wave
// (wave w -> h-cols [16w,16w+16) of k,q,v). x staged in dbuf swizzled LDS,
// one barrier per 64-K tile. B-frags stream from L2-resident Wt.
__global__ __launch_bounds__(256) void qkv_kernel(
    const float* __restrict__ x, const u16* __restrict__ Wt,
    u16* __restrict__ qb, u16* __restrict__ kb, u16* __restrict__ vt) {
  __shared__ u16 xs[2][1024];  // 2 x (16 rows x 64 cols) bf16, XOR-swizzled
  const int tid = threadIdx.x;
  const int lane = tid & 63, w = tid >> 6;
  const int l15 = lane & 15, l4 = lane >> 4;
  const int m0 = blockIdx.x * 16;

  // staging coords: thread -> (row, 4-col chunk)
  const int srow = tid >> 4, sc4 = tid & 15;
  const float* xsrc = x + (size_t)(m0 + srow) * kC + sc4 * 4;
  const int sidx = (srow * 64 + sc4 * 4) ^ ((srow & 7) << 3);

  f32x4 acc[3];
#pragma unroll
  for (int mat = 0; mat < 3; ++mat) acc[mat] = f32x4{0.f, 0.f, 0.f, 0.f};

  const u16* wbase = Wt + (size_t)(w * 16 + l15) * 1024 + 8 * l4;
  const int ra0 = (l15 * 64 + 8 * l4) ^ ((l15 & 7) << 3);
  const int ra1 = (l15 * 64 + 32 + 8 * l4) ^ ((l15 & 7) << 3);

  // stage tile 0
  {
    const float4 xv = *reinterpret_cast<const float4*>(xsrc);
    uint2 pk;
    pk.x = (unsigned)f2bu(xv.x) | ((unsigned)f2bu(xv.y) << 16);
    pk.y = (unsigned)f2bu(xv.z) | ((unsigned)f2bu(xv.w) << 16);
    *reinterpret_cast<uint2*>(&xs[0][sidx]) = pk;
  }
  for (int t = 0; t < 16; ++t) {
    __syncthreads();  // stage(t) visible; compute(t-1) done
    if (t < 15) {
      const float4 xv = *reinterpret_cast<const float4*>(xsrc + (t + 1) * 64);
      uint2 pk;
      pk.x = (unsigned)f2bu(xv.x) | ((unsigned)f2bu(xv.y) << 16);
      pk.y = (unsigned)f2bu(xv.z) | ((unsigned)f2bu(xv.w) << 16);
      *reinterpret_cast<uint2*>(&xs[(t + 1) & 1][sidx]) = pk;
    }
    const u16* xb = xs[t & 1];
    const bf16x8 a0 = *reinterpret_cast<const bf16x8*>(&xb[ra0]);
    const bf16x8 a1 = *reinterpret_cast<const bf16x8*>(&xb[ra1]);
    const int k0 = t * 64;
#pragma unroll
    for (int mat = 0; mat < 3; ++mat) {
      const u16* wp = wbase + (size_t)mat * 64 * 1024 + k0;
      const bf16x8 b0 = *reinterpret_cast<const bf16x8*>(wp);
      const bf16x8 b1 = *reinterpret_cast<const bf16x8*>(wp + 32);
      acc[mat] = mfma16(a0, b0, acc[mat]);
      acc[mat] = mfma16(a1, b1, acc[mat]);
    }
  }
  // D: row = 4*l4 + r, col(h) = 16*w + l15
  const int hcol = w * 16 + l15;
#pragma unroll
  for (int mat = 0; mat < 3; ++mat) {
#pragma unroll
    for (int r = 0; r < 4; ++r) {
      const int m = m0 + 4 * l4 + r;
      const u16 val = f2bu(acc[mat][r]);
      if (mat == 0) kb[(size_t)m * 64 + hcol] = val;
      else if (mat == 1) qb[(size_t)m * 64 + hcol] = val;
      else vt[((size_t)((m >> 11) * 64 + hcol)) * 2048 + (m & 2047)] = val;
    }
  }
}

// K2: l[b,s] = sum_{t>=s} exp(scale * q_t.k_s).  mfma(A=K, B=Q) -> D[s][t].
__global__ __launch_bounds__(256) void colsum_kernel(
    const u16* __restrict__ qb, const u16* __restrict__ kb, float* __restrict__ lG) {
  const int s0 = blockIdx.x * 64;
  const int tc = blockIdx.y * 512;
  const int b = blockIdx.z;
  if (tc + 511 < s0) return;
  const int tid = threadIdx.x;
  const int lane = tid & 63, w = tid >> 6;
  const int l15 = lane & 15, l4 = lane >> 4;

  bf16x8 ka[4][2];
#pragma unroll
  for (int i = 0; i < 4; ++i) {
    const u16* kp = kb + (size_t)(b * kT + s0 + 16 * i + l15) * 64 + 8 * l4;
    ka[i][0] = *reinterpret_cast<const bf16x8*>(kp);
    ka[i][1] = *reinterpret_cast<const bf16x8*>(kp + 32);
  }
  f32x4 cs[4];
#pragma unroll
  for (int i = 0; i < 4; ++i) cs[i] = f32x4{0.f, 0.f, 0.f, 0.f};

  const int d0 = s0 - tc - 128 * w;
  const int jstart = (d0 > 0) ? (d0 >> 4) : 0;  // first frag with any t >= s0
  for (int j = jstart; j < 8; ++j) {
    const int tj = tc + 128 * w + 16 * j;
    const u16* qp = qb + (size_t)(b * kT + tj + l15) * 64 + 8 * l4;
    const bf16x8 qf0 = *reinterpret_cast<const bf16x8*>(qp);
    const bf16x8 qf1 = *reinterpret_cast<const bf16x8*>(qp + 32);
    const int t = tj + l15;
#pragma unroll
    for (int i = 0; i < 4; ++i) {
      f32x4 d = f32x4{0.f, 0.f, 0.f, 0.f};
      d = mfma16(ka[i][0], qf0, d);
      d = mfma16(ka[i][1], qf1, d);
#pragma unroll
      for (int r = 0; r < 4; ++r) {
        const int s = s0 + 16 * i + 4 * l4 + r;
        if (t >= s) cs[i][r] += __expf(d[r] * kScale);
      }
    }
  }
#pragma unroll
  for (int i = 0; i < 4; ++i) {
#pragma unroll
    for (int r = 0; r < 4; ++r) {
      float v = cs[i][r];
      v += __shfl_xor(v, 1, 64);
      v += __shfl_xor(v, 2, 64);
      v += __shfl_xor(v, 4, 64);
      v += __shfl_xor(v, 8, 64);
      if (l15 == 0) atomicAdd(&lG[b * kT + s0 + 16 * i + 4 * l4 + r], v);
    }
  }
}

// K3: out[t,h] = sum_{s<=t} exp(scale*q.k)/l[s] * v[s,h].
// 4-wave blocks, shared t-tile of 16; wave w does s-tiles js = w, w+4, ...
// Deterministic LDS reduce across waves, single coalesced store, no atomics.
__global__ __launch_bounds__(256) void out_kernel(
    const u16* __restrict__ qb, const u16* __restrict__ kb, const u16* __restrict__ vt,
    const float* __restrict__ lG, float* __restrict__ out) {
  __shared__ u16 pl[4][1024];       // per-wave P tile, XOR-swizzled
  __shared__ float red[4][16][64];  // per-wave partial output
  const int tt = blockIdx.x;
  const int b = blockIdx.y;
  const int t0 = tt * 16;
  const int tid = threadIdx.x;
  const int lane = tid & 63, w = tid >> 6;
  const int l15 = lane & 15, l4 = lane >> 4;

  const u16* qp = qb + (size_t)(b * kT + t0 + l15) * 64 + 8 * l4;
  const bf16x8 qf0 = *reinterpret_cast<const bf16x8*>(qp);
  const bf16x8 qf1 = *reinterpret_cast<const bf16x8*>(qp + 32);

  f32x4 acc[4];
#pragma unroll
  for (int nf = 0; nf < 4; ++nf) acc[nf] = f32x4{0.f, 0.f, 0.f, 0.f};

  const int njs = (t0 + 15) / 64 + 1;
  for (int js = w; js < njs; js += 4) {
    const int s0 = js * 64;
    // QK^T -> P -> wave-private LDS
#pragma unroll
    for (int jf = 0; jf < 4; ++jf) {
      const u16* kp = kb + (size_t)(b * kT + s0 + 16 * jf + l15) * 64 + 8 * l4;
      const bf16x8 kf0 = *reinterpret_cast<const bf16x8*>(kp);
      const bf16x8 kf1 = *reinterpret_cast<const bf16x8*>(kp + 32);
      f32x4 d = f32x4{0.f, 0.f, 0.f, 0.f};
      d = mfma16(qf0, kf0, d);
      d = mfma16(qf1, kf1, d);
      const int s = s0 + 16 * jf + l15;
      const float rl = 1.0f / lG[b * kT + s];
#pragma unroll
      for (int r = 0; r < 4; ++r) {
        const int rr = 4 * l4 + r;
        const float p = (t0 + rr >= s) ? __expf(d[r] * kScale) * rl : 0.f;
        pl[w][(rr * 64 + 16 * jf + l15) ^ ((rr & 7) << 3)] = f2bu(p);
      }
    }
    // PV: A = P (swizzled 16B reads), B = V^T frags from global
    const bf16x8 pa0 = *reinterpret_cast<const bf16x8*>(
        &pl[w][(l15 * 64 + 8 * l4) ^ ((l15 & 7) << 3)]);
    const bf16x8 pa1 = *reinterpret_cast<const bf16x8*>(
        &pl[w][(l15 * 64 + 32 + 8 * l4) ^ ((l15 & 7) << 3)]);
#pragma unroll
    for (int nf = 0; nf < 4; ++nf) {
      const u16* vp = vt + (size_t)(b * 64 + 16 * nf + l15) * kT + s0 + 8 * l4;
      const bf16x8 vf0 = *reinterpret_cast<const bf16x8*>(vp);
      const bf16x8 vf1 = *reinterpret_cast<const bf16x8*>(vp + 32);
      acc[nf] = mfma16(pa0, vf0, acc[nf]);
      acc[nf] = mfma16(pa1, vf1, acc[nf]);
    }
  }
  // deterministic cross-wave reduce
#pragma unroll
  for (int nf = 0; nf < 4; ++nf) {
#pragma unroll
    for (int r = 0; r < 4; ++r) red[w][4 * l4 + r][16 * nf + l15] = acc[nf][r];
  }
  __syncthreads();
#pragma unroll
  for (int i = 0; i < 4; ++i) {
    const int idx = tid + 256 * i;
    const int r = idx >> 6, h = idx & 63;
    out[(size_t)(b * kT + t0 + r) * 64 + h] =
        red[0][r][h] + red[1][r][h] + red[2][r][h] + red[3][r][h];
  }
}

}  // namespace

extern "C" void kernel_launch(void* const* d_in, const int* in_sizes, int n_in,
                              void* d_out, int out_size, void* d_ws, size_t ws_size,
                              hipStream_t stream) {
  const float* x = (const float*)d_in[0];
  const float* Wk = (const float*)d_in[1];
  const float* Wq = (const float*)d_in[2];
  const float* Wv = (const float*)d_in[3];
  u16* wsu = (u16*)d_ws;
  u16* Wt = wsu + kWtOff;
  u16* qb = wsu + kQbOff;
  u16* kb = wsu + kKbOff;
  u16* vt = wsu + kVtOff;
  float* lG = (float*)(wsu + kLOff);
  float* out = (float*)d_out;

  hipMemsetAsync(lG, 0, kB * kT * sizeof(float), stream);
  wt_kernel<<<dim3(16, 3), dim3(256), 0, stream>>>(Wk, Wq, Wv, Wt);
  qkv_kernel<<<dim3(kB * kT / 16), dim3(256), 0, stream>>>(x, Wt, qb, kb, vt);
  colsum_kernel<<<dim3(kT / 64, 4, kB), dim3(256), 0, stream>>>(qb, kb, lG);
  out_kernel<<<dim3(kT / 16, kB), dim3(256), 0, stream>>>(qb, kb, vt, lG, out);
}

// Round 6
// 115.150 us; speedup vs baseline: 4.3290x; 1.2090x over previous
//
#include <hip/hip_runtime.h>
#include <hip/hip_bf16.h>

namespace {

typedef unsigned short u16;
typedef __attribute__((ext_vector_type(8))) short bf16x8;
typedef __attribute__((ext_vector_type(4))) float f32x4;

constexpr int kB = 8, kT = 2048, kC = 1024, kH = 64;
constexpr float kScale = 0.03125f;  // 1024^-0.5

// workspace layout in u16 elements
constexpr size_t kWtOff = 0;                                 // 3*64*1024
constexpr size_t kQbOff = kWtOff + 3 * 64 * 1024;            // 16384*64
constexpr size_t kKbOff = kQbOff + (size_t)16384 * 64;
constexpr size_t kVtOff = kKbOff + (size_t)16384 * 64;       // v^T [b*64+h][t]
constexpr size_t kLOff  = kVtOff + (size_t)16384 * 64;       // float l[16384]

__device__ __forceinline__ u16 f2bu(float f) {
  __hip_bfloat16 h = __float2bfloat16(f);
  return *reinterpret_cast<u16*>(&h);
}
__device__ __forceinline__ float bu2f(unsigned int u) {
  union { unsigned int i; float f; } w;
  w.i = u << 16;
  return w.f;
}
__device__ __forceinline__ f32x4 mfma16(bf16x8 a, bf16x8 b, f32x4 c) {
  return __builtin_amdgcn_mfma_f32_16x16x32_bf16(a, b, c, 0, 0, 0);
}

// K0: Wt[mat][h][c] = bf16(W[c][h])
__global__ __launch_bounds__(256) void wt_kernel(
    const float* __restrict__ Wk, const float* __restrict__ Wq,
    const float* __restrict__ Wv, u16* __restrict__ Wt) {
  __shared__ float wsm[64 * 65];
  const int c0 = blockIdx.x * 64;
  const int mat = blockIdx.y;
  const float* W = (mat == 0) ? Wk : (mat == 1) ? Wq : Wv;
  const int tid = threadIdx.x;
#pragma unroll
  for (int ii = 0; ii < 4; ++ii) {
    const int p = tid + 256 * ii;
    const int row = p >> 4, col4 = p & 15;
    const float4 wv = *reinterpret_cast<const float4*>(&W[(size_t)(c0 + row) * 64 + col4 * 4]);
    wsm[row * 65 + col4 * 4 + 0] = wv.x;
    wsm[row * 65 + col4 * 4 + 1] = wv.y;
    wsm[row * 65 + col4 * 4 + 2] = wv.z;
    wsm[row * 65 + col4 * 4 + 3] = wv.w;
  }
  __syncthreads();
  const int h = tid & 63, seg = tid >> 6;
#pragma unroll
  for (int i = 0; i < 16; ++i) {
    const int c = seg * 16 + i;
    Wt[((size_t)mat * 64 + h) * 1024 + c0 + c] = f2bu(wsm[c * 65 + h]);
  }
}

// K1: fused q,k,v GEMM. 4-wave blocks, M-tile 16 shared, N-split by wave.
// Pipelined: global x load issued 2 tiles ahead, LDS write 1 tile ahead,
// B-frags prefetched 1 tile ahead. One barrier per 64-K tile.
__global__ __launch_bounds__(256) void qkv_kernel(
    const float* __restrict__ x, const u16* __restrict__ Wt,
    u16* __restrict__ qb, u16* __restrict__ kb, u16* __restrict__ vt) {
  __shared__ u16 xs[2][1024];  // 2 x (16 rows x 64 cols) bf16, XOR-swizzled
  const int tid = threadIdx.x;
  const int lane = tid & 63, w = tid >> 6;
  const int l15 = lane & 15, l4 = lane >> 4;
  const int m0 = blockIdx.x * 16;

  const int srow = tid >> 4, sc4 = tid & 15;
  const float* xsrc = x + (size_t)(m0 + srow) * kC + sc4 * 4;
  const int sidx = (srow * 64 + sc4 * 4) ^ ((srow & 7) << 3);

  f32x4 acc[3];
#pragma unroll
  for (int mat = 0; mat < 3; ++mat) acc[mat] = f32x4{0.f, 0.f, 0.f, 0.f};

  const u16* wbase = Wt + (size_t)(w * 16 + l15) * 1024 + 8 * l4;
  const int ra0 = (l15 * 64 + 8 * l4) ^ ((l15 & 7) << 3);
  const int ra1 = (l15 * 64 + 32 + 8 * l4) ^ ((l15 & 7) << 3);

  // prologue: stage tile 0, issue global load for tile 1, preload B(0)
  {
    const float4 xv = *reinterpret_cast<const float4*>(xsrc);
    uint2 pk;
    pk.x = (unsigned)f2bu(xv.x) | ((unsigned)f2bu(xv.y) << 16);
    pk.y = (unsigned)f2bu(xv.z) | ((unsigned)f2bu(xv.w) << 16);
    *reinterpret_cast<uint2*>(&xs[0][sidx]) = pk;
  }
  float4 xnext = *reinterpret_cast<const float4*>(xsrc + 64);
  bf16x8 wf[3][2];
#pragma unroll
  for (int mat = 0; mat < 3; ++mat) {
    const u16* wp = wbase + (size_t)mat * 64 * 1024;
    wf[mat][0] = *reinterpret_cast<const bf16x8*>(wp);
    wf[mat][1] = *reinterpret_cast<const bf16x8*>(wp + 32);
  }
  __syncthreads();

  for (int t = 0; t < 16; ++t) {
    // write stage(t+1) from prefetched xnext; issue load for t+2
    if (t < 15) {
      uint2 pk;
      pk.x = (unsigned)f2bu(xnext.x) | ((unsigned)f2bu(xnext.y) << 16);
      pk.y = (unsigned)f2bu(xnext.z) | ((unsigned)f2bu(xnext.w) << 16);
      *reinterpret_cast<uint2*>(&xs[(t + 1) & 1][sidx]) = pk;
      if (t < 14) xnext = *reinterpret_cast<const float4*>(xsrc + (t + 2) * 64);
    }
    const u16* xb = xs[t & 1];
    const bf16x8 a0 = *reinterpret_cast<const bf16x8*>(&xb[ra0]);
    const bf16x8 a1 = *reinterpret_cast<const bf16x8*>(&xb[ra1]);
    // prefetch next tile's B-frags
    bf16x8 wn[3][2];
    if (t < 15) {
      const int k1 = (t + 1) * 64;
#pragma unroll
      for (int mat = 0; mat < 3; ++mat) {
        const u16* wp = wbase + (size_t)mat * 64 * 1024 + k1;
        wn[mat][0] = *reinterpret_cast<const bf16x8*>(wp);
        wn[mat][1] = *reinterpret_cast<const bf16x8*>(wp + 32);
      }
    }
#pragma unroll
    for (int mat = 0; mat < 3; ++mat) {
      acc[mat] = mfma16(a0, wf[mat][0], acc[mat]);
      acc[mat] = mfma16(a1, wf[mat][1], acc[mat]);
    }
#pragma unroll
    for (int mat = 0; mat < 3; ++mat) {
      wf[mat][0] = wn[mat][0];
      wf[mat][1] = wn[mat][1];
    }
    __syncthreads();
  }
  const int hcol = w * 16 + l15;
#pragma unroll
  for (int mat = 0; mat < 3; ++mat) {
#pragma unroll
    for (int r = 0; r < 4; ++r) {
      const int m = m0 + 4 * l4 + r;
      const u16 val = f2bu(acc[mat][r]);
      if (mat == 0) kb[(size_t)m * 64 + hcol] = val;
      else if (mat == 1) qb[(size_t)m * 64 + hcol] = val;
      else vt[((size_t)((m >> 11) * 64 + hcol)) * 2048 + (m & 2047)] = val;
    }
  }
}

// K2: l[b,s] = sum_{t>=s} exp(scale * q_t.k_s).  mfma(A=K, B=Q) -> D[s][t].
__global__ __launch_bounds__(256) void colsum_kernel(
    const u16* __restrict__ qb, const u16* __restrict__ kb, float* __restrict__ lG) {
  const int s0 = blockIdx.x * 64;
  const int tc = blockIdx.y * 512;
  const int b = blockIdx.z;
  if (tc + 511 < s0) return;
  const int tid = threadIdx.x;
  const int lane = tid & 63, w = tid >> 6;
  const int l15 = lane & 15, l4 = lane >> 4;

  bf16x8 ka[4][2];
#pragma unroll
  for (int i = 0; i < 4; ++i) {
    const u16* kp = kb + (size_t)(b * kT + s0 + 16 * i + l15) * 64 + 8 * l4;
    ka[i][0] = *reinterpret_cast<const bf16x8*>(kp);
    ka[i][1] = *reinterpret_cast<const bf16x8*>(kp + 32);
  }
  f32x4 cs[4];
#pragma unroll
  for (int i = 0; i < 4; ++i) cs[i] = f32x4{0.f, 0.f, 0.f, 0.f};

  const int d0 = s0 - tc - 128 * w;
  const int jstart = (d0 > 0) ? (d0 >> 4) : 0;
  const u16* qbase = qb + (size_t)(b * kT + tc + 128 * w + l15) * 64 + 8 * l4;
  bf16x8 qf0, qf1;
  if (jstart < 8) {
    qf0 = *reinterpret_cast<const bf16x8*>(qbase + (size_t)jstart * 1024);
    qf1 = *reinterpret_cast<const bf16x8*>(qbase + (size_t)jstart * 1024 + 32);
  }
  for (int j = jstart; j < 8; ++j) {
    bf16x8 qn0, qn1;
    if (j < 7) {
      qn0 = *reinterpret_cast<const bf16x8*>(qbase + (size_t)(j + 1) * 1024);
      qn1 = *reinterpret_cast<const bf16x8*>(qbase + (size_t)(j + 1) * 1024 + 32);
    }
    const int t = tc + 128 * w + 16 * j + l15;
#pragma unroll
    for (int i = 0; i < 4; ++i) {
      f32x4 d = f32x4{0.f, 0.f, 0.f, 0.f};
      d = mfma16(ka[i][0], qf0, d);
      d = mfma16(ka[i][1], qf1, d);
#pragma unroll
      for (int r = 0; r < 4; ++r) {
        const int s = s0 + 16 * i + 4 * l4 + r;
        if (t >= s) cs[i][r] += __expf(d[r] * kScale);
      }
    }
    qf0 = qn0; qf1 = qn1;
  }
#pragma unroll
  for (int i = 0; i < 4; ++i) {
#pragma unroll
    for (int r = 0; r < 4; ++r) {
      float v = cs[i][r];
      v += __shfl_xor(v, 1, 64);
      v += __shfl_xor(v, 2, 64);
      v += __shfl_xor(v, 4, 64);
      v += __shfl_xor(v, 8, 64);
      if (l15 == 0) atomicAdd(&lG[b * kT + s0 + 16 * i + 4 * l4 + r], v);
    }
  }
}

// K2.5: vt[b*64+h][s] *= 1/l[b][s]  (fold normalizer into V^T)
__global__ __launch_bounds__(256) void vscale_kernel(
    u16* __restrict__ vt, const float* __restrict__ lG) {
  const int idx = blockIdx.x * 256 + threadIdx.x;  // 131072 uint4 chunks
  const int row = idx >> 8;
  const int tc = (idx & 255) * 8;
  const int b = row >> 6;
  u16* vp = vt + (size_t)row * 2048 + tc;
  uint4 pv = *reinterpret_cast<const uint4*>(vp);
  const float* lp = lG + b * 2048 + tc;
  const float4 la = *reinterpret_cast<const float4*>(lp);
  const float4 lb = *reinterpret_cast<const float4*>(lp + 4);
  uint4 ov;
  ov.x = (unsigned)f2bu(bu2f(pv.x & 0xffffu) / la.x) |
         ((unsigned)f2bu(bu2f(pv.x >> 16) / la.y) << 16);
  ov.y = (unsigned)f2bu(bu2f(pv.y & 0xffffu) / la.z) |
         ((unsigned)f2bu(bu2f(pv.y >> 16) / la.w) << 16);
  ov.z = (unsigned)f2bu(bu2f(pv.z & 0xffffu) / lb.x) |
         ((unsigned)f2bu(bu2f(pv.z >> 16) / lb.y) << 16);
  ov.w = (unsigned)f2bu(bu2f(pv.w & 0xffffu) / lb.z) |
         ((unsigned)f2bu(bu2f(pv.w >> 16) / lb.w) << 16);
  *reinterpret_cast<uint4*>(vp) = ov;
}

// K3: out[t,h] = sum_{s<=t} exp(scale*q.k) * vhat[s,h].
// Block = t-tile pair (x, 127-x): uniform work. 4 waves share the t-tile,
// s-striped; k-frags prefetched 1 iter ahead; vhat-frags issued early.
// Deterministic LDS reduce, single coalesced store, no atomics.
__global__ __launch_bounds__(256) void out_kernel(
    const u16* __restrict__ qb, const u16* __restrict__ kb, const u16* __restrict__ vt,
    float* __restrict__ out) {
  __shared__ u16 pl[4][1024];       // per-wave P tile, XOR-swizzled
  __shared__ float red[4][16][64];  // per-wave partial output
  const int pr = blockIdx.x;        // 0..63
  const int b = blockIdx.y;
  const int tid = threadIdx.x;
  const int lane = tid & 63, w = tid >> 6;
  const int l15 = lane & 15, l4 = lane >> 4;
  const size_t bT = (size_t)b * kT;

#pragma unroll
  for (int half = 0; half < 2; ++half) {
    const int tt = half ? (127 - pr) : pr;
    const int t0 = tt * 16;
    const u16* qp = qb + (bT + t0 + l15) * 64 + 8 * l4;
    const bf16x8 qf0 = *reinterpret_cast<const bf16x8*>(qp);
    const bf16x8 qf1 = *reinterpret_cast<const bf16x8*>(qp + 32);

    f32x4 acc[4];
#pragma unroll
    for (int nf = 0; nf < 4; ++nf) acc[nf] = f32x4{0.f, 0.f, 0.f, 0.f};

    const int njs = (t0 + 15) / 64 + 1;
    bf16x8 kf[4][2];
    int js = w;
    if (js < njs) {
      const int s0 = js * 64;
#pragma unroll
      for (int jf = 0; jf < 4; ++jf) {
        const u16* kp = kb + (bT + s0 + 16 * jf + l15) * 64 + 8 * l4;
        kf[jf][0] = *reinterpret_cast<const bf16x8*>(kp);
        kf[jf][1] = *reinterpret_cast<const bf16x8*>(kp + 32);
      }
    }
    for (; js < njs; js += 4) {
      const int s0 = js * 64;
      // vhat frags: issued now, consumed after the P LDS round-trip
      bf16x8 vf[4][2];
#pragma unroll
      for (int nf = 0; nf < 4; ++nf) {
        const u16* vp = vt + (size_t)(b * 64 + 16 * nf + l15) * kT + s0 + 8 * l4;
        vf[nf][0] = *reinterpret_cast<const bf16x8*>(vp);
        vf[nf][1] = *reinterpret_cast<const bf16x8*>(vp + 32);
      }
      // QK^T -> P -> wave-private LDS
#pragma unroll
      for (int jf = 0; jf < 4; ++jf) {
        f32x4 d = f32x4{0.f, 0.f, 0.f, 0.f};
        d = mfma16(qf0, kf[jf][0], d);
        d = mfma16(qf1, kf[jf][1], d);
        const int s = s0 + 16 * jf + l15;
#pragma unroll
        for (int r = 0; r < 4; ++r) {
          const int rr = 4 * l4 + r;
          const float p = (t0 + rr >= s) ? __expf(d[r] * kScale) : 0.f;
          pl[w][(rr * 64 + 16 * jf + l15) ^ ((rr & 7) << 3)] = f2bu(p);
        }
      }
      // prefetch next iteration's k-frags (current ones consumed)
      const int jn = js + 4;
      if (jn < njs) {
        const int sn = jn * 64;
#pragma unroll
        for (int jf = 0; jf < 4; ++jf) {
          const u16* kp = kb + (bT + sn + 16 * jf + l15) * 64 + 8 * l4;
          kf[jf][0] = *reinterpret_cast<const bf16x8*>(kp);
          kf[jf][1] = *reinterpret_cast<const bf16x8*>(kp + 32);
        }
      }
      // PV
      const bf16x8 pa0 = *reinterpret_cast<const bf16x8*>(
          &pl[w][(l15 * 64 + 8 * l4) ^ ((l15 & 7) << 3)]);
      const bf16x8 pa1 = *reinterpret_cast<const bf16x8*>(
          &pl[w][(l15 * 64 + 32 + 8 * l4) ^ ((l15 & 7) << 3)]);
#pragma unroll
      for (int nf = 0; nf < 4; ++nf) {
        acc[nf] = mfma16(pa0, vf[nf][0], acc[nf]);
        acc[nf] = mfma16(pa1, vf[nf][1], acc[nf]);
      }
    }
    // deterministic cross-wave reduce
#pragma unroll
    for (int nf = 0; nf < 4; ++nf) {
#pragma unroll
      for (int r = 0; r < 4; ++r) red[w][4 * l4 + r][16 * nf + l15] = acc[nf][r];
    }
    __syncthreads();
#pragma unroll
    for (int i = 0; i < 4; ++i) {
      const int idx = tid + 256 * i;
      const int r = idx >> 6, h = idx & 63;
      out[(bT + t0 + r) * 64 + h] =
          red[0][r][h] + red[1][r][h] + red[2][r][h] + red[3][r][h];
    }
    __syncthreads();  // protect red before next half rewrites it
  }
}

}  // namespace

extern "C" void kernel_launch(void* const* d_in, const int* in_sizes, int n_in,
                              void* d_out, int out_size, void* d_ws, size_t ws_size,
                              hipStream_t stream) {
  const float* x = (const float*)d_in[0];
  const float* Wk = (const float*)d_in[1];
  const float* Wq = (const float*)d_in[2];
  const float* Wv = (const float*)d_in[3];
  u16* wsu = (u16*)d_ws;
  u16* Wt = wsu + kWtOff;
  u16* qb = wsu + kQbOff;
  u16* kb = wsu + kKbOff;
  u16* vt = wsu + kVtOff;
  float* lG = (float*)(wsu + kLOff);
  float* out = (float*)d_out;

  hipMemsetAsync(lG, 0, kB * kT * sizeof(float), stream);
  wt_kernel<<<dim3(16, 3), dim3(256), 0, stream>>>(Wk, Wq, Wv, Wt);
  qkv_kernel<<<dim3(kB * kT / 16), dim3(256), 0, stream>>>(x, Wt, qb, kb, vt);
  colsum_kernel<<<dim3(kT / 64, 4, kB), dim3(256), 0, stream>>>(qb, kb, lG);
  vscale_kernel<<<dim3(512), dim3(256), 0, stream>>>(vt, lG);
  out_kernel<<<dim3(64, kB), dim3(256), 0, stream>>>(qb, kb, vt, out);
}